// Round 5
// baseline (393.253 us; speedup 1.0000x reference)
//
#include <hip/hip_runtime.h>
#include <math.h>
#include <stdint.h>

// SoftAttention B=32, L=1024, D=256 fp32 via split-bf16 MFMA flash attention.
// R5: 512-thread blocks (BM=128, 2 waves/SIMD), both directions in one
// dispatch, P-lo chain dropped, S corrections merged into one accumulator,
// prepass restructured to 1024 blocks.

#define NB    32
#define SEQ   1024
#define DIM   256
#define BM    128
#define BN    64
#define SHIFT 60.0f
#define PS    1048   // Ph ushort stride per koct (131*8): b128-aligned, bank-spread

typedef unsigned int uint;
typedef unsigned short ushort;
typedef __attribute__((ext_vector_type(8)))  short short8;
typedef __attribute__((ext_vector_type(16))) float f32x16;

// ws layout (ushort units)
#define HL_BATCH  (64 * 1024 * 8)            // [dimoct64][seq1024][8]  (hi=0..31, lo=32..63)
#define HL_TENSOR ((size_t)NB * HL_BATCH)    // 32 MB
#define T_BATCH   (128 * 256 * 8)            // [seqoct128][dim256][8]
#define T_TENSOR  ((size_t)NB * T_BATCH)     // 16 MB
#define WS_NEED   ((2 * HL_TENSOR + 2 * T_TENSOR) * sizeof(ushort))  // ~96 MB

__device__ __forceinline__ ushort bf16_rn(float x) {
    union { float f; uint u; } v; v.f = x;
    uint r = v.u + 0x7fffu + ((v.u >> 16) & 1u);
    return (ushort)(r >> 16);
}
__device__ __forceinline__ float bf16_to_f(ushort h) {
    union { uint u; float f; } v; v.u = ((uint)h) << 16;
    return v.f;
}
__device__ __forceinline__ void gl_lds16(const ushort* g, ushort* l) {
    __builtin_amdgcn_global_load_lds(
        (const __attribute__((address_space(1))) void*)g,
        (__attribute__((address_space(3))) void*)l, 16, 0, 0);
}

// ---------------- pre-pass: fp32 -> octet bf16 hi/lo + transposed hi ----------------
#define TSTR 264
__global__ __launch_bounds__(256)
void prepass(const float* __restrict__ A, const float* __restrict__ Bt,
             ushort* __restrict__ aHL, ushort* __restrict__ bHL,
             ushort* __restrict__ aT,  ushort* __restrict__ bT)
{
    const int tensor = blockIdx.z;
    const float* src = tensor ? Bt : A;
    ushort* hl = tensor ? bHL : aHL;
    ushort* tp = tensor ? bT  : aT;
    const int batch = blockIdx.y;
    const int tid   = threadIdx.x;

    __shared__ float tile[8 * TSTR];

    ushort* hlb = hl + (size_t)batch * HL_BATCH;

    for (int it = 0; it < 8; ++it) {
        const int soct = blockIdx.x * 8 + it;    // 0..127
        const int s0   = soct * 8;
        if (it) __syncthreads();                 // tile reuse guard

        const float* sb = src + ((size_t)batch * SEQ + s0) * DIM;
        #pragma unroll
        for (int i = 0; i < 2; ++i) {
            int idx = tid + i * 256;             // float4 index, 512 total
            int r = idx >> 6, c = idx & 63;
            float4 v = *((const float4*)(sb + (size_t)r * DIM) + c);
            *(float4*)&tile[r * TSTR + c * 4] = v;
        }
        __syncthreads();

        // hi/lo octet writes: 256 tasks = 32 dimocts x 8 rows (hi AND lo each)
        {
            int oct = tid >> 3, srow = tid & 7;
            short8 hv, lv;
            #pragma unroll
            for (int j = 0; j < 8; ++j) {
                float f = tile[srow * TSTR + oct * 8 + j];
                ushort h = bf16_rn(f);
                hv[j] = (short)h;
                lv[j] = (short)bf16_rn(f - bf16_to_f(h));
            }
            *(short8*)(hlb + (size_t)oct * 8192 + (size_t)(s0 + srow) * 8)        = hv;
            *(short8*)(hlb + (size_t)(oct + 32) * 8192 + (size_t)(s0 + srow) * 8) = lv;
        }

        // transposed hi writes: [seqoct][dim][8]
        {
            ushort* tpb = tp + (size_t)batch * T_BATCH + (size_t)soct * 2048;
            int d = tid;
            short8 hv;
            #pragma unroll
            for (int j = 0; j < 8; ++j)
                hv[j] = (short)bf16_rn(tile[j * TSTR + d]);
            *(short8*)(tpb + (size_t)d * 8) = hv;
        }
    }
}

// ---------------- main kernel: both directions, 512 threads ----------------
__global__ __launch_bounds__(512, 2)
void attend3(const ushort* __restrict__ aHL, const ushort* __restrict__ bHL,
             const ushort* __restrict__ aT,  const ushort* __restrict__ bT,
             const int*    __restrict__ ma,  const int*    __restrict__ mb,
             float*        __restrict__ out)
{
    __shared__ __align__(16) ushort Ks2[64 * 512];   // [dimoct64][key64][8] 64 KB
    __shared__ __align__(16) ushort Vt2[8 * 2048];   // [koct8][dim256][8]   32 KB
    __shared__ __align__(16) ushort Ph[8 * PS];      // [koct8][qrow128][8]  16.4 KB
    __shared__ float lpart[2][BM];
    __shared__ float invs[BM];

    const int dir = blockIdx.z;
    const ushort* hlX = dir ? bHL : aHL;
    const ushort* hlY = dir ? aHL : bHL;
    const ushort* tY  = dir ? aT  : bT;
    const int*    mx  = dir ? mb  : ma;
    const int*    my  = dir ? ma  : mb;
    float* o = out + (size_t)dir * NB * SEQ * DIM;

    const int tid  = threadIdx.x;
    const int lane = tid & 63;
    const int wave = tid >> 6;     // 0..7
    const int l31  = lane & 31;
    const int lh   = lane >> 5;
    const int rw   = wave >> 1;    // 0..3 (row block)
    const int cw   = wave & 1;     // 0..1 (key half / dim half)
    const int batch = blockIdx.y;
    const int row0  = blockIdx.x * BM;

    const ushort* hlXb = hlX + (size_t)batch * HL_BATCH;
    const ushort* hlYb = hlY + (size_t)batch * HL_BATCH;
    const ushort* tYb  = tY  + (size_t)batch * T_BATCH;

    // staging bases: wave w stages K dimocts w*8..w*8+7 and V koct w
    const ushort* ksrc = hlYb + (size_t)(wave * 8) * 8192 + (size_t)lane * 8;
    ushort*       kdst = Ks2 + wave * 8 * 512 + lane * 8;
    const ushort* vsrc = tYb + (size_t)wave * 2048 + (size_t)lane * 8;
    ushort*       vdst = Vt2 + wave * 2048 + lane * 8;

    // issue K(0), V(0)
    #pragma unroll
    for (int i = 0; i < 8; ++i) gl_lds16(ksrc + (size_t)i * 8192, kdst + i * 512);
    #pragma unroll
    for (int i = 0; i < 4; ++i) gl_lds16(vsrc + i * 512, vdst + i * 512);

    // Q fragments (hi+lo): A-frag m = l31, k-octet = 2kk+lh
    const int qrow = row0 + rw * 32 + l31;
    short8 qhi[16], qlo[16];
    {
        const ushort* qb = hlXb + (size_t)lh * 8192 + (size_t)qrow * 8;
        #pragma unroll
        for (int kk = 0; kk < 16; ++kk) {
            qhi[kk] = *(const short8*)(qb + (size_t)(2 * kk) * 8192);
            qlo[kk] = *(const short8*)(qb + (size_t)(2 * kk + 32) * 8192);
        }
    }

    f32x16 oacc[4];
    #pragma unroll
    for (int t = 0; t < 4; ++t)
        #pragma unroll
        for (int r = 0; r < 16; ++r) oacc[t][r] = 0.f;
    float lsum[16];
    #pragma unroll
    for (int r = 0; r < 16; ++r) lsum[r] = 0.f;

    __syncthreads();   // drains K(0), V(0)

    for (int nt = 0; nt < SEQ / BN; ++nt) {
        const int key0 = nt * BN;
        const float mkv = (float)my[batch * SEQ + key0 + cw * 32 + l31];

        // ---- S phase: a1 = Qhi·Khi ; a2 = Qlo·Khi + Qhi·Klo ----
        f32x16 a1, a2;
        #pragma unroll
        for (int r = 0; r < 16; ++r) { a1[r] = 0.f; a2[r] = 0.f; }
        const int kcol = (cw * 32 + l31) * 8;
        #pragma unroll
        for (int kk = 0; kk < 16; ++kk) {
            short8 bhi = *(const short8*)&Ks2[(2 * kk + lh) * 512 + kcol];
            a1 = __builtin_amdgcn_mfma_f32_32x32x16_bf16(qhi[kk], bhi, a1, 0, 0, 0);
            a2 = __builtin_amdgcn_mfma_f32_32x32x16_bf16(qlo[kk], bhi, a2, 0, 0, 0);
        }
        #pragma unroll
        for (int kk = 0; kk < 16; ++kk) {
            short8 blo = *(const short8*)&Ks2[(2 * kk + lh + 32) * 512 + kcol];
            a2 = __builtin_amdgcn_mfma_f32_32x32x16_bf16(qhi[kk], blo, a2, 0, 0, 0);
        }

        // ---- fixed-shift exp, l-partials, pack P-hi to LDS ----
        const int key  = cw * 32 + l31;
        const int koct = key >> 3, kj = key & 7;
        #pragma unroll
        for (int r = 0; r < 16; ++r) {
            float s = a1[r] + a2[r];
            float p = __expf(s - SHIFT) * mkv;
            lsum[r] += p;
            int qr = rw * 32 + (r & 3) + ((r >> 2) << 3) + (lh << 2);
            Ph[koct * PS + qr * 8 + kj] = bf16_rn(p);
        }
        __syncthreads();   // P visible; Ks2 free

        // prefetch K(nt+1) — flies during PV, drained at next barrier
        if (nt + 1 < SEQ / BN) {
            const ushort* ks = ksrc + (size_t)(key0 + BN) * 8;
            #pragma unroll
            for (int i = 0; i < 8; ++i) gl_lds16(ks + (size_t)i * 8192, kdst + i * 512);
        }

        // ---- PV phase: oacc += Phi·Vhi ----
        const int prow = (rw * 32 + l31) * 8;
        #pragma unroll
        for (int kb = 0; kb < 4; ++kb) {
            short8 pa = *(const short8*)&Ph[(2 * kb + lh) * PS + prow];
            #pragma unroll
            for (int t = 0; t < 4; ++t) {
                int dim = cw * 128 + t * 32 + l31;
                short8 vf = *(const short8*)&Vt2[(2 * kb + lh) * 2048 + dim * 8];
                oacc[t] = __builtin_amdgcn_mfma_f32_32x32x16_bf16(pa, vf, oacc[t], 0, 0, 0);
            }
        }
        __syncthreads();   // Vt2/Ph free; drains K(nt+1)

        // prefetch V(nt+1) — flies during next S phase
        if (nt + 1 < SEQ / BN) {
            const ushort* vs = vsrc + ((size_t)(key0 + BN) >> 3) * 2048;
            #pragma unroll
            for (int i = 0; i < 4; ++i) gl_lds16(vs + i * 512, vdst + i * 512);
        }
    }

    // ---- epilogue: reduce l, normalize, store ----
    #pragma unroll
    for (int r = 0; r < 16; ++r) {
        float v = lsum[r];
        v += __shfl_xor(v, 1, 64);
        v += __shfl_xor(v, 2, 64);
        v += __shfl_xor(v, 4, 64);
        v += __shfl_xor(v, 8, 64);
        v += __shfl_xor(v, 16, 64);
        if (l31 == 0) {
            int row = rw * 32 + (r & 3) + ((r >> 2) << 3) + (lh << 2);
            lpart[cw][row] = v;
        }
    }
    __syncthreads();
    if (tid < BM) {
        float l = lpart[0][tid] + lpart[1][tid];
        int valid = mx[batch * SEQ + row0 + tid];
        invs[tid] = (valid != 0 && l > 0.f) ? 1.f / l : 0.f;
    }
    __syncthreads();

    float* ob = o + ((size_t)batch * SEQ + row0) * DIM;
    #pragma unroll
    for (int r = 0; r < 16; ++r) {
        int rloc = rw * 32 + (r & 3) + ((r >> 2) << 3) + (lh << 2);
        float inv = invs[rloc];
        #pragma unroll
        for (int t = 0; t < 4; ++t) {
            int d = cw * 128 + t * 32 + l31;
            ob[(size_t)rloc * DIM + d] = oacc[t][r] * inv;
        }
    }
}

// ---------------- fallback (R2 kernel, known-good) if ws too small ----------------
#define F_KS_STR 520
#define F_P_STR  136
#define F_BM 64
#define F_BN 64
__global__ __launch_bounds__(256, 1)
void attend_mfma(const float* __restrict__ X, const float* __restrict__ Y,
                 const int* __restrict__ mx, const int* __restrict__ my,
                 float* __restrict__ out)
{
    __shared__ ushort Ks[F_BN * F_KS_STR];
    __shared__ ushort Ps[F_BM * F_P_STR];
    __shared__ float  mk[F_BN];
    __shared__ float  lpart[2][F_BM];
    __shared__ float  invs[F_BM];

    const int tid = threadIdx.x, lane = tid & 63, wave = tid >> 6;
    const int l31 = lane & 31, lh = lane >> 5;
    const int rw = wave >> 1, cw = wave & 1;
    const int batch = blockIdx.y, row0 = blockIdx.x * F_BM;
    const float* Xb = X + (size_t)batch * SEQ * DIM;
    const float* Yb = Y + (size_t)batch * SEQ * DIM;

    float4 kreg[16]; int mreg = 0;
    #pragma unroll
    for (int i = 0; i < 16; ++i) {
        int idx = tid + (i << 8); int r = idx >> 6, c4 = idx & 63;
        kreg[i] = *((const float4*)(Yb + (size_t)r * DIM) + c4);
    }
    if (tid < F_BN) mreg = my[batch * SEQ + tid];

    short8 qhi[16], qlo[16];
    {
        const float* qrow = Xb + (size_t)(row0 + rw * 32 + l31) * DIM + lh * 8;
        #pragma unroll
        for (int kk = 0; kk < 16; ++kk) {
            const float* p = qrow + kk * 16;
            float4 x0 = *(const float4*)p; float4 x1 = *(const float4*)(p + 4);
            float xs[8] = {x0.x, x0.y, x0.z, x0.w, x1.x, x1.y, x1.z, x1.w};
            #pragma unroll
            for (int j = 0; j < 8; ++j) {
                ushort h = bf16_rn(xs[j]);
                qhi[kk][j] = (short)h;
                qlo[kk][j] = (short)bf16_rn(xs[j] - bf16_to_f(h));
            }
        }
    }
    f32x16 oacc[4];
    #pragma unroll
    for (int t = 0; t < 4; ++t)
        #pragma unroll
        for (int r = 0; r < 16; ++r) oacc[t][r] = 0.f;
    float lsum[16];
    #pragma unroll
    for (int r = 0; r < 16; ++r) lsum[r] = 0.f;

    for (int nt = 0; nt < SEQ / F_BN; ++nt) {
        if (nt) __syncthreads();
        #pragma unroll
        for (int i = 0; i < 16; ++i) {
            int idx = tid + (i << 8); int r = idx >> 6, c4 = idx & 63;
            float f[4] = {kreg[i].x, kreg[i].y, kreg[i].z, kreg[i].w};
            ushort hh[4], ll[4];
            #pragma unroll
            for (int q = 0; q < 4; ++q) { hh[q] = bf16_rn(f[q]); ll[q] = bf16_rn(f[q] - bf16_to_f(hh[q])); }
            ushort4 hv; hv.x=hh[0];hv.y=hh[1];hv.z=hh[2];hv.w=hh[3];
            ushort4 lv; lv.x=ll[0];lv.y=ll[1];lv.z=ll[2];lv.w=ll[3];
            *(ushort4*)&Ks[r * F_KS_STR + c4 * 4] = hv;
            *(ushort4*)&Ks[r * F_KS_STR + 256 + c4 * 4] = lv;
        }
        if (tid < F_BN) mk[tid] = (float)mreg;
        __syncthreads();
        if (nt + 1 < SEQ / F_BN) {
            const float* Ybn = Yb + (size_t)(nt + 1) * F_BN * DIM;
            #pragma unroll
            for (int i = 0; i < 16; ++i) {
                int idx = tid + (i << 8); int r = idx >> 6, c4 = idx & 63;
                kreg[i] = *((const float4*)(Ybn + (size_t)r * DIM) + c4);
            }
            if (tid < F_BN) mreg = my[batch * SEQ + (nt + 1) * F_BN + tid];
        }
        f32x16 a1, a2, a3;
        #pragma unroll
        for (int r = 0; r < 16; ++r) { a1[r]=0.f; a2[r]=0.f; a3[r]=0.f; }
        const int krow = (cw * 32 + l31) * F_KS_STR;
        #pragma unroll
        for (int kk = 0; kk < 16; ++kk) {
            int col = kk * 16 + lh * 8;
            short8 bhi = *(const short8*)&Ks[krow + col];
            short8 blo = *(const short8*)&Ks[krow + 256 + col];
            a1 = __builtin_amdgcn_mfma_f32_32x32x16_bf16(qhi[kk], bhi, a1, 0, 0, 0);
            a2 = __builtin_amdgcn_mfma_f32_32x32x16_bf16(qlo[kk], bhi, a2, 0, 0, 0);
            a3 = __builtin_amdgcn_mfma_f32_32x32x16_bf16(qhi[kk], blo, a3, 0, 0, 0);
        }
        const float mkv = mk[cw * 32 + l31];
        #pragma unroll
        for (int r = 0; r < 16; ++r) {
            float s = a1[r] + a2[r] + a3[r];
            float p = __expf(s - SHIFT) * mkv;
            lsum[r] += p;
            ushort ph = bf16_rn(p);
            ushort pl = bf16_rn(p - bf16_to_f(ph));
            int prow = rw * 32 + (r & 3) + ((r >> 2) << 3) + (lh << 2);
            int pcol = cw * 32 + l31;
            Ps[prow * F_P_STR + pcol] = ph;
            Ps[prow * F_P_STR + 64 + pcol] = pl;
        }
        __syncthreads();
        const int prow = (rw * 32 + l31) * F_P_STR;
        #pragma unroll
        for (int kb = 0; kb < 4; ++kb) {
            int pcol = kb * 16 + lh * 8;
            short8 pa_hi = *(const short8*)&Ps[prow + pcol];
            short8 pa_lo = *(const short8*)&Ps[prow + 64 + pcol];
            #pragma unroll
            for (int t = 0; t < 4; ++t) {
                int d0 = cw * 128 + t * 32 + l31;
                short8 vf;
                #pragma unroll
                for (int j = 0; j < 8; ++j) vf[j] = (short)Ks[(pcol + j) * F_KS_STR + d0];
                oacc[t] = __builtin_amdgcn_mfma_f32_32x32x16_bf16(pa_hi, vf, oacc[t], 0, 0, 0);
                oacc[t] = __builtin_amdgcn_mfma_f32_32x32x16_bf16(pa_lo, vf, oacc[t], 0, 0, 0);
            }
        }
    }
    #pragma unroll
    for (int r = 0; r < 16; ++r) {
        float v = lsum[r];
        v += __shfl_xor(v, 1, 64); v += __shfl_xor(v, 2, 64); v += __shfl_xor(v, 4, 64);
        v += __shfl_xor(v, 8, 64); v += __shfl_xor(v, 16, 64);
        if (l31 == 0) {
            int row = rw * 32 + (r & 3) + ((r >> 2) << 3) + (lh << 2);
            lpart[cw][row] = v;
        }
    }
    __syncthreads();
    if (tid < F_BM) {
        float l = lpart[0][tid] + lpart[1][tid];
        int valid = mx[batch * SEQ + row0 + tid];
        invs[tid] = (valid != 0 && l > 0.f) ? 1.f / l : 0.f;
    }
    __syncthreads();
    float* ob = out + ((size_t)batch * SEQ + row0) * DIM;
    #pragma unroll
    for (int r = 0; r < 16; ++r) {
        int rloc = rw * 32 + (r & 3) + ((r >> 2) << 3) + (lh << 2);
        float inv = invs[rloc];
        #pragma unroll
        for (int t = 0; t < 4; ++t) {
            int d = cw * 128 + t * 32 + l31;
            ob[(size_t)rloc * DIM + d] = oacc[t][r] * inv;
        }
    }
}

extern "C" void kernel_launch(void* const* d_in, const int* in_sizes, int n_in,
                              void* d_out, int out_size, void* d_ws, size_t ws_size,
                              hipStream_t stream) {
    const float* a  = (const float*)d_in[0];
    const float* b  = (const float*)d_in[1];
    const int*   ma = (const int*)d_in[2];
    const int*   mb = (const int*)d_in[3];
    float* out = (float*)d_out;

    if (ws_size >= WS_NEED) {
        ushort* wsu = (ushort*)d_ws;
        ushort* aHL = wsu;
        ushort* bHL = wsu + HL_TENSOR;
        ushort* aT  = wsu + 2 * HL_TENSOR;
        ushort* bT  = wsu + 2 * HL_TENSOR + T_TENSOR;

        prepass<<<dim3(SEQ / 64, NB, 2), 256, 0, stream>>>(a, b, aHL, bHL, aT, bT);
        attend3<<<dim3(SEQ / BM, NB, 2), 512, 0, stream>>>(aHL, bHL, aT, bT, ma, mb, out);
    } else {
        float* out_a = out;
        float* out_b = out + (size_t)NB * SEQ * DIM;
        dim3 grid(SEQ / F_BM, NB), block(256);
        attend_mfma<<<grid, block, 0, stream>>>(a, b, ma, mb, out_a);
        attend_mfma<<<grid, block, 0, stream>>>(b, a, mb, ma, out_b);
    }
}

// Round 6
// 329.322 us; speedup vs baseline: 1.1941x; 1.1941x over previous
//
#include <hip/hip_runtime.h>
#include <math.h>
#include <stdint.h>

// SoftAttention B=32, L=1024, D=256 fp32 via split-bf16 MFMA flash attention.
// R6 = R5 + XCD-pinned block swizzle (all 8 row-blocks of a (batch,dir) pair
// land on one XCD -> L2 serves the shared K/V stream; R5's linear mapping put
// them on 8 different XCDs -> 8x fetch amplification, 597 MB FETCH_SIZE),
// prepass hi/lo phase reads global directly (was 16-way LDS bank conflicts),
// per-block mask preload.

#define NB    32
#define SEQ   1024
#define DIM   256
#define BM    128
#define BN    64
#define SHIFT 60.0f
#define PS    1048   // Ph ushort stride per koct: b128-aligned, bank-spread

typedef unsigned int uint;
typedef unsigned short ushort;
typedef __attribute__((ext_vector_type(8)))  short short8;
typedef __attribute__((ext_vector_type(16))) float f32x16;

// ws layout (ushort units)
#define HL_BATCH  (64 * 1024 * 8)            // [dimoct64][seq1024][8]  (hi=0..31, lo=32..63)
#define HL_TENSOR ((size_t)NB * HL_BATCH)    // 32 MB
#define T_BATCH   (128 * 256 * 8)            // [seqoct128][dim256][8]
#define T_TENSOR  ((size_t)NB * T_BATCH)     // 16 MB
#define WS_NEED   ((2 * HL_TENSOR + 2 * T_TENSOR) * sizeof(ushort))  // ~96 MB

__device__ __forceinline__ ushort bf16_rn(float x) {
    union { float f; uint u; } v; v.f = x;
    uint r = v.u + 0x7fffu + ((v.u >> 16) & 1u);
    return (ushort)(r >> 16);
}
__device__ __forceinline__ float bf16_to_f(ushort h) {
    union { uint u; float f; } v; v.u = ((uint)h) << 16;
    return v.f;
}
__device__ __forceinline__ void gl_lds16(const ushort* g, ushort* l) {
    __builtin_amdgcn_global_load_lds(
        (const __attribute__((address_space(1))) void*)g,
        (__attribute__((address_space(3))) void*)l, 16, 0, 0);
}

// ---------------- pre-pass: fp32 -> octet bf16 hi/lo + transposed hi ----------------
#define TSTR 264
__global__ __launch_bounds__(256)
void prepass(const float* __restrict__ A, const float* __restrict__ Bt,
             ushort* __restrict__ aHL, ushort* __restrict__ bHL,
             ushort* __restrict__ aT,  ushort* __restrict__ bT)
{
    const int tensor = blockIdx.z;
    const float* src = tensor ? Bt : A;
    ushort* hl = tensor ? bHL : aHL;
    ushort* tp = tensor ? bT  : aT;
    const int batch = blockIdx.y;
    const int tid   = threadIdx.x;

    __shared__ float tile[8 * TSTR];

    ushort* hlb = hl + (size_t)batch * HL_BATCH;

    for (int it = 0; it < 8; ++it) {
        const int soct = blockIdx.x * 8 + it;    // 0..127
        const int s0   = soct * 8;
        if (it) __syncthreads();                 // tile reuse guard

        // ---- phase A: hi/lo octets straight from global (no LDS, no conflicts)
        // thread = (oct 0..31, srow 0..7); reads 32B/lane, lines fully covered.
        {
            const int oct = tid >> 3, srow = tid & 7;
            const float* rp = src + ((size_t)batch * SEQ + s0 + srow) * DIM + oct * 8;
            float4 x0 = *(const float4*)rp;
            float4 x1 = *(const float4*)(rp + 4);
            float xs[8] = {x0.x, x0.y, x0.z, x0.w, x1.x, x1.y, x1.z, x1.w};
            short8 hv, lv;
            #pragma unroll
            for (int j = 0; j < 8; ++j) {
                ushort h = bf16_rn(xs[j]);
                hv[j] = (short)h;
                lv[j] = (short)bf16_rn(xs[j] - bf16_to_f(h));
            }
            *(short8*)(hlb + (size_t)oct * 8192 + (size_t)(s0 + srow) * 8)        = hv;
            *(short8*)(hlb + (size_t)(oct + 32) * 8192 + (size_t)(s0 + srow) * 8) = lv;
        }

        // ---- phase B: LDS round-trip only for the transpose
        const float* sb = src + ((size_t)batch * SEQ + s0) * DIM;
        #pragma unroll
        for (int i = 0; i < 2; ++i) {
            int idx = tid + i * 256;             // float4 index, 512 total
            int r = idx >> 6, c = idx & 63;
            float4 v = *((const float4*)(sb + (size_t)r * DIM) + c);
            *(float4*)&tile[r * TSTR + c * 4] = v;
        }
        __syncthreads();
        {
            ushort* tpb = tp + (size_t)batch * T_BATCH + (size_t)soct * 2048;
            int d = tid;                          // 0..255; column reads, 2-way ok
            short8 hv;
            #pragma unroll
            for (int j = 0; j < 8; ++j)
                hv[j] = (short)bf16_rn(tile[j * TSTR + d]);
            *(short8*)(tpb + (size_t)d * 8) = hv;
        }
    }
}

// ---------------- main kernel: both directions, 512 threads, XCD-pinned ----------------
__global__ __launch_bounds__(512, 2)
void attend3(const ushort* __restrict__ aHL, const ushort* __restrict__ bHL,
             const ushort* __restrict__ aT,  const ushort* __restrict__ bT,
             const int*    __restrict__ ma,  const int*    __restrict__ mb,
             float*        __restrict__ out)
{
    __shared__ __align__(16) ushort Ks2[64 * 512];   // [dimoct64][key64][8] 64 KB
    __shared__ __align__(16) ushort Vt2[8 * 2048];   // [koct8][dim256][8]   32 KB
    __shared__ __align__(16) ushort Ph[8 * PS];      // [koct8][qrow128][8]  16.4 KB
    __shared__ float msk[SEQ];                       // key mask, 4 KB
    __shared__ float lpart[2][BM];
    __shared__ float invs[BM];

    // XCD-pinning swizzle: linear block -> XCD is round-robin (% 8), so give
    // all 8 row-blocks of one (batch,dir) pair the same residue mod 8.
    const int bx   = blockIdx.x;        // 0..511
    const int xcd  = bx & 7;
    const int slot = bx >> 3;           // 0..63
    const int rb   = slot & 7;          // row-block 0..7
    const int pg   = slot >> 3;         // 0..7
    const int pair = xcd + 8 * pg;      // 0..63, pair%8 == xcd
    const int batch = pair >> 1;
    const int dir   = pair & 1;
    const int row0  = rb * BM;

    const ushort* hlX = dir ? bHL : aHL;
    const ushort* hlY = dir ? aHL : bHL;
    const ushort* tY  = dir ? aT  : bT;
    const int*    mx  = dir ? mb  : ma;
    const int*    my  = dir ? ma  : mb;
    float* o = out + (size_t)dir * NB * SEQ * DIM;

    const int tid  = threadIdx.x;
    const int lane = tid & 63;
    const int wave = tid >> 6;     // 0..7
    const int l31  = lane & 31;
    const int lh   = lane >> 5;
    const int rw   = wave >> 1;    // 0..3 (row block)
    const int cw   = wave & 1;     // 0..1 (key half / dim half)

    const ushort* hlXb = hlX + (size_t)batch * HL_BATCH;
    const ushort* hlYb = hlY + (size_t)batch * HL_BATCH;
    const ushort* tYb  = tY  + (size_t)batch * T_BATCH;

    // staging bases: wave w stages K dimocts w*8..w*8+7 and V koct w
    const ushort* ksrc = hlYb + (size_t)(wave * 8) * 8192 + (size_t)lane * 8;
    ushort*       kdst = Ks2 + wave * 8 * 512 + lane * 8;
    const ushort* vsrc = tYb + (size_t)wave * 2048 + (size_t)lane * 8;
    ushort*       vdst = Vt2 + wave * 2048 + lane * 8;

    // issue K(0), V(0)
    #pragma unroll
    for (int i = 0; i < 8; ++i) gl_lds16(ksrc + (size_t)i * 8192, kdst + i * 512);
    #pragma unroll
    for (int i = 0; i < 4; ++i) gl_lds16(vsrc + i * 512, vdst + i * 512);

    // key-mask preload (coalesced, once per block)
    for (int i = tid; i < SEQ; i += 512) msk[i] = (float)my[batch * SEQ + i];

    // Q fragments (hi+lo): A-frag m = l31, k-octet = 2kk+lh
    const int qrow = row0 + rw * 32 + l31;
    short8 qhi[16], qlo[16];
    {
        const ushort* qb = hlXb + (size_t)lh * 8192 + (size_t)qrow * 8;
        #pragma unroll
        for (int kk = 0; kk < 16; ++kk) {
            qhi[kk] = *(const short8*)(qb + (size_t)(2 * kk) * 8192);
            qlo[kk] = *(const short8*)(qb + (size_t)(2 * kk + 32) * 8192);
        }
    }

    f32x16 oacc[4];
    #pragma unroll
    for (int t = 0; t < 4; ++t)
        #pragma unroll
        for (int r = 0; r < 16; ++r) oacc[t][r] = 0.f;
    float lsum[16];
    #pragma unroll
    for (int r = 0; r < 16; ++r) lsum[r] = 0.f;

    __syncthreads();   // drains K(0), V(0); msk visible

    for (int nt = 0; nt < SEQ / BN; ++nt) {
        const int key0 = nt * BN;
        const float mkv = msk[key0 + cw * 32 + l31];

        // ---- S phase: a1 = Qhi·Khi ; a2 = Qlo·Khi + Qhi·Klo ----
        f32x16 a1, a2;
        #pragma unroll
        for (int r = 0; r < 16; ++r) { a1[r] = 0.f; a2[r] = 0.f; }
        const int kcol = (cw * 32 + l31) * 8;
        #pragma unroll
        for (int kk = 0; kk < 16; ++kk) {
            short8 bhi = *(const short8*)&Ks2[(2 * kk + lh) * 512 + kcol];
            a1 = __builtin_amdgcn_mfma_f32_32x32x16_bf16(qhi[kk], bhi, a1, 0, 0, 0);
            a2 = __builtin_amdgcn_mfma_f32_32x32x16_bf16(qlo[kk], bhi, a2, 0, 0, 0);
        }
        #pragma unroll
        for (int kk = 0; kk < 16; ++kk) {
            short8 blo = *(const short8*)&Ks2[(2 * kk + lh + 32) * 512 + kcol];
            a2 = __builtin_amdgcn_mfma_f32_32x32x16_bf16(qhi[kk], blo, a2, 0, 0, 0);
        }

        // ---- fixed-shift exp, l-partials, pack P-hi to LDS ----
        const int key  = cw * 32 + l31;
        const int koct = key >> 3, kj = key & 7;
        #pragma unroll
        for (int r = 0; r < 16; ++r) {
            float s = a1[r] + a2[r];
            float p = __expf(s - SHIFT) * mkv;
            lsum[r] += p;
            int qr = rw * 32 + (r & 3) + ((r >> 2) << 3) + (lh << 2);
            Ph[koct * PS + qr * 8 + kj] = bf16_rn(p);
        }
        __syncthreads();   // P visible; Ks2 free

        // prefetch K(nt+1) — flies during PV, drained at next barrier
        if (nt + 1 < SEQ / BN) {
            const ushort* ks = ksrc + (size_t)(key0 + BN) * 8;
            #pragma unroll
            for (int i = 0; i < 8; ++i) gl_lds16(ks + (size_t)i * 8192, kdst + i * 512);
        }

        // ---- PV phase: oacc += Phi·Vhi ----
        const int prow = (rw * 32 + l31) * 8;
        #pragma unroll
        for (int kb = 0; kb < 4; ++kb) {
            short8 pa = *(const short8*)&Ph[(2 * kb + lh) * PS + prow];
            #pragma unroll
            for (int t = 0; t < 4; ++t) {
                int dim = cw * 128 + t * 32 + l31;
                short8 vf = *(const short8*)&Vt2[(2 * kb + lh) * 2048 + dim * 8];
                oacc[t] = __builtin_amdgcn_mfma_f32_32x32x16_bf16(pa, vf, oacc[t], 0, 0, 0);
            }
        }
        __syncthreads();   // Vt2/Ph free; drains K(nt+1)

        // prefetch V(nt+1) — flies during next S phase
        if (nt + 1 < SEQ / BN) {
            const ushort* vs = vsrc + ((size_t)(key0 + BN) >> 3) * 2048;
            #pragma unroll
            for (int i = 0; i < 4; ++i) gl_lds16(vs + i * 512, vdst + i * 512);
        }
    }

    // ---- epilogue: reduce l, normalize, store ----
    #pragma unroll
    for (int r = 0; r < 16; ++r) {
        float v = lsum[r];
        v += __shfl_xor(v, 1, 64);
        v += __shfl_xor(v, 2, 64);
        v += __shfl_xor(v, 4, 64);
        v += __shfl_xor(v, 8, 64);
        v += __shfl_xor(v, 16, 64);
        if (l31 == 0) {
            int row = rw * 32 + (r & 3) + ((r >> 2) << 3) + (lh << 2);
            lpart[cw][row] = v;
        }
    }
    __syncthreads();
    if (tid < BM) {
        float l = lpart[0][tid] + lpart[1][tid];
        int valid = mx[batch * SEQ + row0 + tid];
        invs[tid] = (valid != 0 && l > 0.f) ? 1.f / l : 0.f;
    }
    __syncthreads();

    float* ob = o + ((size_t)batch * SEQ + row0) * DIM;
    #pragma unroll
    for (int r = 0; r < 16; ++r) {
        int rloc = rw * 32 + (r & 3) + ((r >> 2) << 3) + (lh << 2);
        float inv = invs[rloc];
        #pragma unroll
        for (int t = 0; t < 4; ++t) {
            int d = cw * 128 + t * 32 + l31;
            ob[(size_t)rloc * DIM + d] = oacc[t][r] * inv;
        }
    }
}

// ---------------- fallback (R2 kernel, known-good) if ws too small ----------------
#define F_KS_STR 520
#define F_P_STR  136
#define F_BM 64
#define F_BN 64
__global__ __launch_bounds__(256, 1)
void attend_mfma(const float* __restrict__ X, const float* __restrict__ Y,
                 const int* __restrict__ mx, const int* __restrict__ my,
                 float* __restrict__ out)
{
    __shared__ ushort Ks[F_BN * F_KS_STR];
    __shared__ ushort Ps[F_BM * F_P_STR];
    __shared__ float  mk[F_BN];
    __shared__ float  lpart[2][F_BM];
    __shared__ float  invs[F_BM];

    const int tid = threadIdx.x, lane = tid & 63, wave = tid >> 6;
    const int l31 = lane & 31, lh = lane >> 5;
    const int rw = wave >> 1, cw = wave & 1;
    const int batch = blockIdx.y, row0 = blockIdx.x * F_BM;
    const float* Xb = X + (size_t)batch * SEQ * DIM;
    const float* Yb = Y + (size_t)batch * SEQ * DIM;

    float4 kreg[16]; int mreg = 0;
    #pragma unroll
    for (int i = 0; i < 16; ++i) {
        int idx = tid + (i << 8); int r = idx >> 6, c4 = idx & 63;
        kreg[i] = *((const float4*)(Yb + (size_t)r * DIM) + c4);
    }
    if (tid < F_BN) mreg = my[batch * SEQ + tid];

    short8 qhi[16], qlo[16];
    {
        const float* qrow = Xb + (size_t)(row0 + rw * 32 + l31) * DIM + lh * 8;
        #pragma unroll
        for (int kk = 0; kk < 16; ++kk) {
            const float* p = qrow + kk * 16;
            float4 x0 = *(const float4*)p; float4 x1 = *(const float4*)(p + 4);
            float xs[8] = {x0.x, x0.y, x0.z, x0.w, x1.x, x1.y, x1.z, x1.w};
            #pragma unroll
            for (int j = 0; j < 8; ++j) {
                ushort h = bf16_rn(xs[j]);
                qhi[kk][j] = (short)h;
                qlo[kk][j] = (short)bf16_rn(xs[j] - bf16_to_f(h));
            }
        }
    }
    f32x16 oacc[4];
    #pragma unroll
    for (int t = 0; t < 4; ++t)
        #pragma unroll
        for (int r = 0; r < 16; ++r) oacc[t][r] = 0.f;
    float lsum[16];
    #pragma unroll
    for (int r = 0; r < 16; ++r) lsum[r] = 0.f;

    for (int nt = 0; nt < SEQ / F_BN; ++nt) {
        if (nt) __syncthreads();
        #pragma unroll
        for (int i = 0; i < 16; ++i) {
            int idx = tid + (i << 8); int r = idx >> 6, c4 = idx & 63;
            float f[4] = {kreg[i].x, kreg[i].y, kreg[i].z, kreg[i].w};
            ushort hh[4], ll[4];
            #pragma unroll
            for (int q = 0; q < 4; ++q) { hh[q] = bf16_rn(f[q]); ll[q] = bf16_rn(f[q] - bf16_to_f(hh[q])); }
            ushort4 hv; hv.x=hh[0];hv.y=hh[1];hv.z=hh[2];hv.w=hh[3];
            ushort4 lv; lv.x=ll[0];lv.y=ll[1];lv.z=ll[2];lv.w=ll[3];
            *(ushort4*)&Ks[r * F_KS_STR + c4 * 4] = hv;
            *(ushort4*)&Ks[r * F_KS_STR + 256 + c4 * 4] = lv;
        }
        if (tid < F_BN) mk[tid] = (float)mreg;
        __syncthreads();
        if (nt + 1 < SEQ / F_BN) {
            const float* Ybn = Yb + (size_t)(nt + 1) * F_BN * DIM;
            #pragma unroll
            for (int i = 0; i < 16; ++i) {
                int idx = tid + (i << 8); int r = idx >> 6, c4 = idx & 63;
                kreg[i] = *((const float4*)(Ybn + (size_t)r * DIM) + c4);
            }
            if (tid < F_BN) mreg = my[batch * SEQ + (nt + 1) * F_BN + tid];
        }
        f32x16 a1, a2, a3;
        #pragma unroll
        for (int r = 0; r < 16; ++r) { a1[r]=0.f; a2[r]=0.f; a3[r]=0.f; }
        const int krow = (cw * 32 + l31) * F_KS_STR;
        #pragma unroll
        for (int kk = 0; kk < 16; ++kk) {
            int col = kk * 16 + lh * 8;
            short8 bhi = *(const short8*)&Ks[krow + col];
            short8 blo = *(const short8*)&Ks[krow + 256 + col];
            a1 = __builtin_amdgcn_mfma_f32_32x32x16_bf16(qhi[kk], bhi, a1, 0, 0, 0);
            a2 = __builtin_amdgcn_mfma_f32_32x32x16_bf16(qlo[kk], bhi, a2, 0, 0, 0);
            a3 = __builtin_amdgcn_mfma_f32_32x32x16_bf16(qhi[kk], blo, a3, 0, 0, 0);
        }
        const float mkv = mk[cw * 32 + l31];
        #pragma unroll
        for (int r = 0; r < 16; ++r) {
            float s = a1[r] + a2[r] + a3[r];
            float p = __expf(s - SHIFT) * mkv;
            lsum[r] += p;
            ushort ph = bf16_rn(p);
            ushort pl = bf16_rn(p - bf16_to_f(ph));
            int prow = rw * 32 + (r & 3) + ((r >> 2) << 3) + (lh << 2);
            int pcol = cw * 32 + l31;
            Ps[prow * F_P_STR + pcol] = ph;
            Ps[prow * F_P_STR + 64 + pcol] = pl;
        }
        __syncthreads();
        const int prow = (rw * 32 + l31) * F_P_STR;
        #pragma unroll
        for (int kb = 0; kb < 4; ++kb) {
            int pcol = kb * 16 + lh * 8;
            short8 pa_hi = *(const short8*)&Ps[prow + pcol];
            short8 pa_lo = *(const short8*)&Ps[prow + 64 + pcol];
            #pragma unroll
            for (int t = 0; t < 4; ++t) {
                int d0 = cw * 128 + t * 32 + l31;
                short8 vf;
                #pragma unroll
                for (int j = 0; j < 8; ++j) vf[j] = (short)Ks[(pcol + j) * F_KS_STR + d0];
                oacc[t] = __builtin_amdgcn_mfma_f32_32x32x16_bf16(pa_hi, vf, oacc[t], 0, 0, 0);
                oacc[t] = __builtin_amdgcn_mfma_f32_32x32x16_bf16(pa_lo, vf, oacc[t], 0, 0, 0);
            }
        }
    }
    #pragma unroll
    for (int r = 0; r < 16; ++r) {
        float v = lsum[r];
        v += __shfl_xor(v, 1, 64); v += __shfl_xor(v, 2, 64); v += __shfl_xor(v, 4, 64);
        v += __shfl_xor(v, 8, 64); v += __shfl_xor(v, 16, 64);
        if (l31 == 0) {
            int row = rw * 32 + (r & 3) + ((r >> 2) << 3) + (lh << 2);
            lpart[cw][row] = v;
        }
    }
    __syncthreads();
    if (tid < F_BM) {
        float l = lpart[0][tid] + lpart[1][tid];
        int valid = mx[batch * SEQ + row0 + tid];
        invs[tid] = (valid != 0 && l > 0.f) ? 1.f / l : 0.f;
    }
    __syncthreads();
    float* ob = out + ((size_t)batch * SEQ + row0) * DIM;
    #pragma unroll
    for (int r = 0; r < 16; ++r) {
        int rloc = rw * 32 + (r & 3) + ((r >> 2) << 3) + (lh << 2);
        float inv = invs[rloc];
        #pragma unroll
        for (int t = 0; t < 4; ++t) {
            int d = cw * 128 + t * 32 + l31;
            ob[(size_t)rloc * DIM + d] = oacc[t][r] * inv;
        }
    }
}

extern "C" void kernel_launch(void* const* d_in, const int* in_sizes, int n_in,
                              void* d_out, int out_size, void* d_ws, size_t ws_size,
                              hipStream_t stream) {
    const float* a  = (const float*)d_in[0];
    const float* b  = (const float*)d_in[1];
    const int*   ma = (const int*)d_in[2];
    const int*   mb = (const int*)d_in[3];
    float* out = (float*)d_out;

    if (ws_size >= WS_NEED) {
        ushort* wsu = (ushort*)d_ws;
        ushort* aHL = wsu;
        ushort* bHL = wsu + HL_TENSOR;
        ushort* aT  = wsu + 2 * HL_TENSOR;
        ushort* bT  = wsu + 2 * HL_TENSOR + T_TENSOR;

        prepass<<<dim3(SEQ / 64, NB, 2), 256, 0, stream>>>(a, b, aHL, bHL, aT, bT);
        attend3<<<dim3(512, 1, 1), 512, 0, stream>>>(aHL, bHL, aT, bT, ma, mb, out);
    } else {
        float* out_a = out;
        float* out_b = out + (size_t)NB * SEQ * DIM;
        dim3 grid(SEQ / F_BM, NB), block(256);
        attend_mfma<<<grid, block, 0, stream>>>(a, b, ma, mb, out_a);
        attend_mfma<<<grid, block, 0, stream>>>(b, a, mb, ma, out_b);
    }
}